// Round 12
// baseline (217.808 us; speedup 1.0000x reference)
//
#include <hip/hip_runtime.h>
#include <cstddef>

#define B_  16
#define C_  512
#define N_  1024

typedef __attribute__((ext_vector_type(8))) __bf16 bf16x8;
typedef __attribute__((ext_vector_type(4))) float f32x4;
typedef __attribute__((ext_vector_type(4))) short s16x4;

__device__ __forceinline__ unsigned short f2bf(float x) {
  unsigned u = __float_as_uint(x);
  return (unsigned short)((u + 0x7fffu + ((u >> 16) & 1u)) >> 16);
}
__device__ __forceinline__ float bf2f(unsigned short h) {
  return __uint_as_float(((unsigned)h) << 16);
}

#define GLDS16(g, l)                                                            \
  __builtin_amdgcn_global_load_lds(                                             \
      (const __attribute__((address_space(1))) void*)(g),                       \
      (__attribute__((address_space(3))) void*)(l), 16, 0, 0)

// ---------- prep: weight fp32->bf16 (blocks 0..1023) + GN stats (blocks 1024..1535) ----------
__global__ __launch_bounds__(256) void prep_kernel(
    const float* __restrict__ wq, const float* __restrict__ wp,
    unsigned short* __restrict__ oq, unsigned short* __restrict__ op,
    const float* __restrict__ x, float* __restrict__ stats) {
  int tid = threadIdx.x;
  if (blockIdx.x < 1024) {
    int i = blockIdx.x * 256 + tid;  // float4 chunks
    const float4* src; unsigned short* dst; int off;
    if (i < 196608) { src = (const float4*)wq; dst = oq; off = i; }
    else            { src = (const float4*)wp; dst = op; off = i - 196608; }
    float4 v = src[off];
    union { unsigned short s[4]; ushort4 u; } o;
    o.s[0] = f2bf(v.x); o.s[1] = f2bf(v.y);
    o.s[2] = f2bf(v.z); o.s[3] = f2bf(v.w);
    *(ushort4*)(dst + (size_t)off * 4) = o.u;
    return;
  }
  int bg = blockIdx.x - 1024;      // b*32 + g
  int b = bg >> 5, g = bg & 31;
  const float4* x4 = (const float4*)(x + ((size_t)b * C_ + (size_t)g * 16) * N_);
  float sum = 0.f, sq = 0.f;
#pragma unroll
  for (int i = 0; i < 16; i++) {
    float4 v = x4[tid + i * 256];
    sum += v.x + v.y + v.z + v.w;
    sq  += v.x * v.x + v.y * v.y + v.z * v.z + v.w * v.w;
  }
#pragma unroll
  for (int off = 32; off > 0; off >>= 1) {
    sum += __shfl_down(sum, off, 64);
    sq  += __shfl_down(sq, off, 64);
  }
  __shared__ float sm[4], sv[4];
  int lane = tid & 63, w = tid >> 6;
  if (lane == 0) { sm[w] = sum; sv[w] = sq; }
  __syncthreads();
  if (tid == 0) {
    float s = sm[0] + sm[1] + sm[2] + sm[3];
    float q = sv[0] + sv[1] + sv[2] + sv[3];
    float mean = s * (1.f / 16384.f);
    float var  = q * (1.f / 16384.f) - mean * mean;
    stats[bg * 2]     = mean;
    stats[bg * 2 + 1] = rsqrtf(var + 1e-5f);
  }
}

// ---------- GN normalize + transpose: writes hT[b][n][c] in 128B runs ----------
__global__ __launch_bounds__(256) void gn_norm(
    const float* __restrict__ x, const float* __restrict__ gamma,
    const float* __restrict__ beta, const float* __restrict__ stats,
    unsigned short* __restrict__ hT) {
  __shared__ __align__(16) unsigned short T[64][72];  // 144B rows: 16B-aligned

  const int bi = blockIdx.x;              // b*32 + g4*4 + nq
  const int nq = bi & 3, g4 = (bi >> 2) & 7, b = bi >> 5;
  const int tid = threadIdx.x, lane = tid & 63, w = tid >> 6;
  const int c0 = g4 * 64, n0 = nq * 256;
  const int q = lane >> 4, n4 = lane & 15;

  const int gidx = b * 32 + g4 * 4 + w;
  const float mean = stats[gidx * 2], rstd = stats[gidx * 2 + 1];
  float ga[4], be[4];
#pragma unroll
  for (int ri = 0; ri < 4; ri++) {
    int c = w * 16 + q + ri * 4;
    ga[ri] = gamma[c0 + c] * rstd;
    be[ri] = beta[c0 + c] - mean * ga[ri];
  }

  const float* xb = x + ((size_t)b * C_ + c0) * N_ + n0;

#pragma unroll
  for (int s = 0; s < 4; s++) {
#pragma unroll
    for (int ri = 0; ri < 4; ri++) {
      int c = w * 16 + q + ri * 4;
      float4 v = *(const float4*)&xb[(size_t)c * N_ + s * 64 + n4 * 4];
      int csw = c ^ ((n4 & 3) << 4);      // XOR-swizzle 16-col blocks by row
      T[n4 * 4 + 0][csw] = f2bf(v.x * ga[ri] + be[ri]);
      T[n4 * 4 + 1][csw] = f2bf(v.y * ga[ri] + be[ri]);
      T[n4 * 4 + 2][csw] = f2bf(v.z * ga[ri] + be[ri]);
      T[n4 * 4 + 3][csw] = f2bf(v.w * ga[ri] + be[ri]);
    }
    __syncthreads();
    {
      int n_loc = tid >> 2, cc = (tid & 3) << 4;
      int ccs = cc ^ (((n_loc >> 2) & 3) << 4);   // matching swizzle
      const uint4* srcp = (const uint4*)&T[n_loc][ccs];
      uint4* dst = (uint4*)&hT[((size_t)b * N_ + n0 + s * 64 + n_loc) * C_ + c0 + cc];
      dst[0] = srcp[0];
      dst[1] = srcp[1];
    }
    __syncthreads();
  }
}

// ---------- MFMA GEMM: Out[b,m,n] = sum_k W[m,k]*InT[b,n,k] + bias[m] (+resid) ----------
// T4 K-loop: 3 LDS buffers, prefetch distance 2, raw s_barrier + counted
// s_waitcnt vmcnt(4) (never 0 in steady state). Proven round 11 (~25us saved
// across both GEMMs vs the vmcnt(0)-drain loop).
template <int OUT_BF16>
__global__ __launch_bounds__(256) void gemm_mfma(
    const unsigned short* __restrict__ Wb, const float* __restrict__ bias,
    const unsigned short* __restrict__ InT, const float* __restrict__ resid,
    void* __restrict__ Out, int M) {
  // A planes = SH[0..2], B planes = SH[3..5]; kT epilogue aliases SH[0..2]
  __shared__ __align__(16) unsigned short SH[6][128 * 32];

  const int b = blockIdx.z;
  const int n0 = blockIdx.x * 128, m0 = blockIdx.y * 128;
  const int tid = threadIdx.x;
  const int lane = tid & 63, wave = tid >> 6;
  const int col = lane & 15, quad = lane >> 4;
  const int wm = (wave >> 1) << 6, wn = (wave & 1) << 6;

  const unsigned short* Ag = Wb + (size_t)m0 * C_;
  const unsigned short* Bg = InT + ((size_t)b * N_ + n0) * C_;

  const int r0 = tid >> 2, c0 = (tid & 3) << 3;

  auto stage = [&](int buf, int k0) {
    GLDS16(Ag + (size_t)r0 * C_ + k0 + c0,        &SH[buf][tid * 8]);
    GLDS16(Ag + (size_t)(r0 + 64) * C_ + k0 + c0, &SH[buf][(tid + 256) * 8]);
    GLDS16(Bg + (size_t)r0 * C_ + k0 + c0,        &SH[3 + buf][tid * 8]);
    GLDS16(Bg + (size_t)(r0 + 64) * C_ + k0 + c0, &SH[3 + buf][(tid + 256) * 8]);
  };

  f32x4 acc[4][4];
#pragma unroll
  for (int i = 0; i < 4; i++)
#pragma unroll
    for (int j = 0; j < 4; j++) acc[i][j] = f32x4{0.f, 0.f, 0.f, 0.f};

  // prologue: tiles 0,1 in flight; wait tile0 only (4 newest may fly)
  stage(0, 0);
  stage(1, 32);
  asm volatile("s_waitcnt vmcnt(4)\n\ts_barrier" ::: "memory");

  for (int it = 0; it < 16; it++) {
    const int cur = it % 3;
    if (it < 14) stage((it + 2) % 3, (it + 2) * 32);  // prefetch distance 2

    bf16x8 af[4], bfr[4];
#pragma unroll
    for (int mt = 0; mt < 4; mt++)
      af[mt] = *(const bf16x8*)&SH[cur][(wm + mt * 16 + col) * 32 + quad * 8];
#pragma unroll
    for (int nt = 0; nt < 4; nt++)
      bfr[nt] = *(const bf16x8*)&SH[3 + cur][(wn + nt * 16 + col) * 32 + quad * 8];
#pragma unroll
    for (int mt = 0; mt < 4; mt++)
#pragma unroll
      for (int nt = 0; nt < 4; nt++)
        acc[mt][nt] = __builtin_amdgcn_mfma_f32_16x16x32_bf16(
            af[mt], bfr[nt], acc[mt][nt], 0, 0, 0);

    if (it < 14) {
      asm volatile("s_waitcnt vmcnt(4)\n\ts_barrier" ::: "memory");
    } else if (it == 14) {
      asm volatile("s_waitcnt vmcnt(0)\n\ts_barrier" ::: "memory");
    }
  }

  const bool kT = OUT_BF16 && (m0 >= 512) && (m0 < 1024);

  if (kT) {
    // Transposed K output via LDS: epi[64 n][136 shorts] per n-half.
    unsigned short* epi = &SH[0][0];
    unsigned short* kt_out =
        (unsigned short*)Out + ((size_t)b * 1536 + 512) * N_ + (m0 - 512);
#pragma unroll
    for (int hf = 0; hf < 2; hf++) {
      __syncthreads();
      if ((wave & 1) == hf) {
#pragma unroll
        for (int mt = 0; mt < 4; mt++) {
          int mloc = wm + mt * 16 + quad * 4;      // 0..127 within block tile
          int mabs = m0 + mloc;
#pragma unroll
          for (int nt = 0; nt < 4; nt++) {
            union { unsigned short s[4]; ushort4 v; } o;
#pragma unroll
            for (int r = 0; r < 4; r++)
              o.s[r] = f2bf(acc[mt][nt][r] + bias[mabs + r]);
            *(ushort4*)&epi[(nt * 16 + col) * 136 + mloc] = o.v;
          }
        }
      }
      __syncthreads();
#pragma unroll
      for (int pass = 0; pass < 4; pass++) {
        int n_l = (tid >> 4) + pass * 16;
        int ch = tid & 15;
        uint4 v = *(const uint4*)&epi[n_l * 136 + ch * 8];
        *(uint4*)(kt_out + (size_t)(n0 + hf * 64 + n_l) * 512 + ch * 8) = v;
      }
    }
    return;
  }

#pragma unroll
  for (int mt = 0; mt < 4; mt++) {
    int mbase = m0 + wm + mt * 16 + quad * 4;
#pragma unroll
    for (int nt = 0; nt < 4; nt++) {
      int n = n0 + wn + nt * 16 + col;
      if constexpr (OUT_BF16) {
#pragma unroll
        for (int r = 0; r < 4; r++) {
          float v = acc[mt][nt][r] + bias[mbase + r];
          ((unsigned short*)Out)[((size_t)b * M + mbase + r) * N_ + n] = f2bf(v);
        }
      } else {
#pragma unroll
        for (int r = 0; r < 4; r++) {
          int m = mbase + r;
          float v = acc[mt][nt][r] + bias[m];
          size_t off = ((size_t)b * M + m) * N_ + n;
          ((float*)Out)[off] = v + resid[off];
        }
      }
    }
  }
}

// ---------- MFMA flash attention, no-max softmax ----------
// Round-12: T4 counted-vmcnt ported from the GEMM. 3 K/V buffers (48KB LDS),
// prefetch distance 2, s_waitcnt vmcnt(4) + s_barrier per tile (vmcnt(0) only
// at tile 14). Round-11 counters: attn 63us vs ~25us pipe-work bound, with the
// per-tile __syncthreads draining the just-issued next-tile loads (vmcnt0) at
// every barrier -- same stall the GEMM had before T4.
// Race audit: buffer (kt+2)%3 written at kt was last read at kt-1, before that
// barrier; per-wave vmcnt(4) before barrier lands each wave's own staged
// quarter of tile kt+1; ds_reads drain via MFMA data deps before barrier.
__device__ __forceinline__ void attn_tile(const bf16x8 (&qf)[2][2],
                                          const bf16x8 (&kf)[4][2],
                                          const s16x4 (&vf)[4][4],
                                          f32x4 (&O)[4][2], float (&l_i)[2]) {
#pragma unroll
  for (int nt = 0; nt < 2; nt++) {
    f32x4 sf[4];
#pragma unroll
    for (int mt = 0; mt < 4; mt++) sf[mt] = f32x4{0.f, 0.f, 0.f, 0.f};
    __builtin_amdgcn_s_setprio(1);
#pragma unroll
    for (int ks = 0; ks < 2; ks++)
#pragma unroll
      for (int mt = 0; mt < 4; mt++)
        sf[mt] = __builtin_amdgcn_mfma_f32_16x16x32_bf16(
            kf[mt][ks], qf[nt][ks], sf[mt], 0, 0, 0);
    __builtin_amdgcn_s_setprio(0);

    // p = exp(s); pack to bf16 by truncation (1 v_perm per pair)
    s16x4 pb[4];
    float lsum = 0.f;
#pragma unroll
    for (int kc = 0; kc < 4; kc++) {
      float e0 = __expf(sf[kc][0]);
      float e1 = __expf(sf[kc][1]);
      float e2 = __expf(sf[kc][2]);
      float e3 = __expf(sf[kc][3]);
      lsum += (e0 + e1) + (e2 + e3);
      unsigned lo = __builtin_amdgcn_perm(__float_as_uint(e1), __float_as_uint(e0), 0x07060302u);
      unsigned hi = __builtin_amdgcn_perm(__float_as_uint(e3), __float_as_uint(e2), 0x07060302u);
      union { unsigned u[2]; s16x4 v; } t;
      t.u[0] = lo; t.u[1] = hi;
      pb[kc] = t.v;
    }
    l_i[nt] += lsum;

    __builtin_amdgcn_s_setprio(1);
#pragma unroll
    for (int kc = 0; kc < 4; kc++)
#pragma unroll
      for (int mt = 0; mt < 4; mt++)
        O[mt][nt] = __builtin_amdgcn_mfma_f32_16x16x16bf16_1k(
            vf[mt][kc], pb[kc], O[mt][nt], 0, 0, 0);
    __builtin_amdgcn_s_setprio(0);
  }
}

template <int NB, int BOFF>
__global__ __launch_bounds__(256, 2) void attn_mfma(
    const unsigned short* __restrict__ qkv, unsigned short* __restrict__ aoT) {
  __shared__ __align__(16) unsigned short KtL[3][64 * 64];
  __shared__ __align__(16) unsigned short VsL[3][64 * 64];

  const int tid = threadIdx.x;
  const int wave = tid >> 6, lane = tid & 63;
  const int quad = lane >> 4, col = lane & 15;
  const int bi = blockIdx.x;
  const int hh = bi & 7;                    // bi%8==head -> XCD-grouped
  const int bq = bi >> 3;                   // 0 .. 8*NB-1
  const int qb = bq / NB;                   // 0..7 (compile-time div)
  const int b  = BOFF + (bq - qb * NB);
  const int qblk = qb * 128 + wave * 32;

  const unsigned short* qp  = qkv + ((size_t)b * 1536 + hh * 64) * N_;           // [d][N]
  const unsigned short* ktp = qkv + ((size_t)b * 1536 + 512) * N_ + hh * 64;     // [key][512]
  const unsigned short* vp  = qkv + ((size_t)b * 1536 + 1024 + hh * 64) * N_;    // [d][N]

  // staging decomposition: row within half-tile + swizzled 16B chunk
  const int sr = tid >> 3;                          // 0..31
  const int sw8 = (((tid & 7) ^ (sr & 7)) << 3);    // swizzled chunk, in shorts

  auto stage = [&](int buf, int kt) {
    const unsigned short* kq = ktp + (size_t)(kt * 64 + sr) * 512 + sw8;
    GLDS16(kq,                    &KtL[buf][tid * 8]);
    GLDS16(kq + (size_t)32 * 512, &KtL[buf][(256 + tid) * 8]);
    const unsigned short* vq = vp + (size_t)sr * N_ + kt * 64 + sw8;
    GLDS16(vq,                    &VsL[buf][tid * 8]);
    GLDS16(vq + (size_t)32 * N_,  &VsL[buf][(256 + tid) * 8]);
  };

  // Q B-fragments pre-scaled by 0.125 (exact: exponent shift under RNE).
  bf16x8 qf[2][2];
#pragma unroll
  for (int nt = 0; nt < 2; nt++) {
    int qg = qblk + nt * 16 + col;
#pragma unroll
    for (int ks = 0; ks < 2; ks++) {
      union { unsigned short s[8]; bf16x8 v; } t;
#pragma unroll
      for (int j = 0; j < 8; j++) {
        int d = ks * 32 + quad * 8 + j;
        t.s[j] = f2bf(0.125f * bf2f(qp[(size_t)d * N_ + qg]));
      }
      qf[nt][ks] = t.v;
    }
  }

  float l_i[2];
  f32x4 O[4][2];
#pragma unroll
  for (int nt = 0; nt < 2; nt++) {
    l_i[nt] = 0.f;
#pragma unroll
    for (int mt = 0; mt < 4; mt++) O[mt][nt] = f32x4{0.f, 0.f, 0.f, 0.f};
  }

  // prologue: tiles 0,1 in flight; wait tile0 only (4 newest may fly)
  stage(0, 0);
  stage(1, 1);
  asm volatile("s_waitcnt vmcnt(4)\n\ts_barrier" ::: "memory");

  for (int kt = 0; kt < 16; kt++) {
    const int cur = kt % 3;
    if (kt < 14) stage((kt + 2) % 3, kt + 2);  // prefetch distance 2

    // K A-fragments (16x16x32): b128, swizzle-matched
    bf16x8 kf[4][2];
#pragma unroll
    for (int mt = 0; mt < 4; mt++) {
      int key = 16 * mt + col;
#pragma unroll
      for (int ks = 0; ks < 2; ks++)
        kf[mt][ks] = *(const bf16x8*)
            &KtL[cur][key * 64 + (((ks * 4 + quad) ^ (col & 7)) << 3)];
    }
    // V A-fragments (16x16x16): b64, swizzle-matched at 8B granularity
    s16x4 vf[4][4];
#pragma unroll
    for (int mt = 0; mt < 4; mt++) {
      int d = 16 * mt + col;
#pragma unroll
      for (int kc = 0; kc < 4; kc++)
        vf[mt][kc] = *(const s16x4*)
            &VsL[cur][d * 64 + (((kc * 4 + quad) ^ ((col & 7) << 1)) << 2)];
    }

    attn_tile(qf, kf, vf, O, l_i);

    if (kt < 14) {
      asm volatile("s_waitcnt vmcnt(4)\n\ts_barrier" ::: "memory");
    } else if (kt == 14) {
      asm volatile("s_waitcnt vmcnt(0)\n\ts_barrier" ::: "memory");
    }
  }

#pragma unroll
  for (int nt = 0; nt < 2; nt++) {
    float ls = l_i[nt];
    ls += __shfl_xor(ls, 16, 64);
    ls += __shfl_xor(ls, 32, 64);
    float inv = 1.f / ls;
    int qg = qblk + nt * 16 + col;
    unsigned short* dst = aoT + ((size_t)b * N_ + qg) * C_ + hh * 64;
#pragma unroll
    for (int mt = 0; mt < 4; mt++) {
      union { unsigned short s[4]; ushort4 v; } o;
#pragma unroll
      for (int r = 0; r < 4; r++) o.s[r] = f2bf(O[mt][nt][r] * inv);
      *(ushort4*)(dst + mt * 16 + quad * 4) = o.v;
    }
  }
}

extern "C" void kernel_launch(void* const* d_in, const int* in_sizes, int n_in,
                              void* d_out, int out_size, void* d_ws, size_t ws_size,
                              hipStream_t stream) {
  (void)in_sizes; (void)n_in; (void)out_size; (void)ws_size;
  const float* x      = (const float*)d_in[0];
  const float* gamma  = (const float*)d_in[1];
  const float* beta   = (const float*)d_in[2];
  const float* w_qkv  = (const float*)d_in[3];
  const float* b_qkv  = (const float*)d_in[4];
  const float* w_proj = (const float*)d_in[5];
  const float* b_proj = (const float*)d_in[6];
  float* out = (float*)d_out;

  unsigned short* hT   = (unsigned short*)d_ws;                 // B*N*C bf16
  unsigned short* qkvb = hT + (size_t)B_ * N_ * C_;             // B*3C*N bf16 (K region = KT[b][n][512])
  unsigned short* aoT  = hT;                                    // reuse
  unsigned short* wqb  = qkvb + (size_t)B_ * 1536 * N_;         // 3C*C bf16
  unsigned short* wpb  = wqb + (size_t)1536 * 512;              // C*C bf16
  float* stats = (float*)(wpb + (size_t)512 * 512);             // 512 x {mean,rstd}

  prep_kernel<<<dim3(1024 + 512), dim3(256), 0, stream>>>(w_qkv, w_proj, wqb, wpb, x, stats);
  gn_norm<<<dim3(512), dim3(256), 0, stream>>>(x, gamma, beta, stats, hT);
  gemm_mfma<1><<<dim3(8, 12, 16), dim3(256), 0, stream>>>(
      wqb, b_qkv, hT, (const float*)nullptr, (void*)qkvb, 1536);
  attn_mfma<16, 0><<<dim3(1024), dim3(256), 0, stream>>>(qkvb, aoT);
  gemm_mfma<0><<<dim3(8, 4, 16), dim3(256), 0, stream>>>(
      wpb, b_proj, aoT, x, (void*)out, 512);
}

// Round 13
// 211.374 us; speedup vs baseline: 1.0304x; 1.0304x over previous
//
#include <hip/hip_runtime.h>
#include <cstddef>

#define B_  16
#define C_  512
#define N_  1024

typedef __attribute__((ext_vector_type(8))) __bf16 bf16x8;
typedef __attribute__((ext_vector_type(4))) float f32x4;
typedef __attribute__((ext_vector_type(4))) short s16x4;

__device__ __forceinline__ unsigned short f2bf(float x) {
  unsigned u = __float_as_uint(x);
  return (unsigned short)((u + 0x7fffu + ((u >> 16) & 1u)) >> 16);
}
__device__ __forceinline__ float bf2f(unsigned short h) {
  return __uint_as_float(((unsigned)h) << 16);
}

#define GLDS16(g, l)                                                            \
  __builtin_amdgcn_global_load_lds(                                             \
      (const __attribute__((address_space(1))) void*)(g),                       \
      (__attribute__((address_space(3))) void*)(l), 16, 0, 0)

// ---------- prep: weight fp32->bf16 (blocks 0..1023) + GN stats (blocks 1024..1535) ----------
__global__ __launch_bounds__(256) void prep_kernel(
    const float* __restrict__ wq, const float* __restrict__ wp,
    unsigned short* __restrict__ oq, unsigned short* __restrict__ op,
    const float* __restrict__ x, float* __restrict__ stats) {
  int tid = threadIdx.x;
  if (blockIdx.x < 1024) {
    int i = blockIdx.x * 256 + tid;  // float4 chunks
    const float4* src; unsigned short* dst; int off;
    if (i < 196608) { src = (const float4*)wq; dst = oq; off = i; }
    else            { src = (const float4*)wp; dst = op; off = i - 196608; }
    float4 v = src[off];
    union { unsigned short s[4]; ushort4 u; } o;
    o.s[0] = f2bf(v.x); o.s[1] = f2bf(v.y);
    o.s[2] = f2bf(v.z); o.s[3] = f2bf(v.w);
    *(ushort4*)(dst + (size_t)off * 4) = o.u;
    return;
  }
  int bg = blockIdx.x - 1024;      // b*32 + g
  int b = bg >> 5, g = bg & 31;
  const float4* x4 = (const float4*)(x + ((size_t)b * C_ + (size_t)g * 16) * N_);
  float sum = 0.f, sq = 0.f;
#pragma unroll
  for (int i = 0; i < 16; i++) {
    float4 v = x4[tid + i * 256];
    sum += v.x + v.y + v.z + v.w;
    sq  += v.x * v.x + v.y * v.y + v.z * v.z + v.w * v.w;
  }
#pragma unroll
  for (int off = 32; off > 0; off >>= 1) {
    sum += __shfl_down(sum, off, 64);
    sq  += __shfl_down(sq, off, 64);
  }
  __shared__ float sm[4], sv[4];
  int lane = tid & 63, w = tid >> 6;
  if (lane == 0) { sm[w] = sum; sv[w] = sq; }
  __syncthreads();
  if (tid == 0) {
    float s = sm[0] + sm[1] + sm[2] + sm[3];
    float q = sv[0] + sv[1] + sv[2] + sv[3];
    float mean = s * (1.f / 16384.f);
    float var  = q * (1.f / 16384.f) - mean * mean;
    stats[bg * 2]     = mean;
    stats[bg * 2 + 1] = rsqrtf(var + 1e-5f);
  }
}

// ---------- GN normalize + transpose: writes hT[b][n][c] in 128B runs ----------
__global__ __launch_bounds__(256) void gn_norm(
    const float* __restrict__ x, const float* __restrict__ gamma,
    const float* __restrict__ beta, const float* __restrict__ stats,
    unsigned short* __restrict__ hT) {
  __shared__ __align__(16) unsigned short T[64][72];  // 144B rows: 16B-aligned

  const int bi = blockIdx.x;              // b*32 + g4*4 + nq
  const int nq = bi & 3, g4 = (bi >> 2) & 7, b = bi >> 5;
  const int tid = threadIdx.x, lane = tid & 63, w = tid >> 6;
  const int c0 = g4 * 64, n0 = nq * 256;
  const int q = lane >> 4, n4 = lane & 15;

  const int gidx = b * 32 + g4 * 4 + w;
  const float mean = stats[gidx * 2], rstd = stats[gidx * 2 + 1];
  float ga[4], be[4];
#pragma unroll
  for (int ri = 0; ri < 4; ri++) {
    int c = w * 16 + q + ri * 4;
    ga[ri] = gamma[c0 + c] * rstd;
    be[ri] = beta[c0 + c] - mean * ga[ri];
  }

  const float* xb = x + ((size_t)b * C_ + c0) * N_ + n0;

#pragma unroll
  for (int s = 0; s < 4; s++) {
#pragma unroll
    for (int ri = 0; ri < 4; ri++) {
      int c = w * 16 + q + ri * 4;
      float4 v = *(const float4*)&xb[(size_t)c * N_ + s * 64 + n4 * 4];
      int csw = c ^ ((n4 & 3) << 4);      // XOR-swizzle 16-col blocks by row
      T[n4 * 4 + 0][csw] = f2bf(v.x * ga[ri] + be[ri]);
      T[n4 * 4 + 1][csw] = f2bf(v.y * ga[ri] + be[ri]);
      T[n4 * 4 + 2][csw] = f2bf(v.z * ga[ri] + be[ri]);
      T[n4 * 4 + 3][csw] = f2bf(v.w * ga[ri] + be[ri]);
    }
    __syncthreads();
    {
      int n_loc = tid >> 2, cc = (tid & 3) << 4;
      int ccs = cc ^ (((n_loc >> 2) & 3) << 4);   // matching swizzle
      const uint4* srcp = (const uint4*)&T[n_loc][ccs];
      uint4* dst = (uint4*)&hT[((size_t)b * N_ + n0 + s * 64 + n_loc) * C_ + c0 + cc];
      dst[0] = srcp[0];
      dst[1] = srcp[1];
    }
    __syncthreads();
  }
}

// ---------- MFMA GEMM: Out[b,m,n] = sum_k W[m,k]*InT[b,n,k] + bias[m] (+resid) ----------
// T4 K-loop: 3 LDS buffers, prefetch distance 2, raw s_barrier + counted
// s_waitcnt vmcnt(4) (never 0 in steady state). Proven round 11.
template <int OUT_BF16>
__global__ __launch_bounds__(256) void gemm_mfma(
    const unsigned short* __restrict__ Wb, const float* __restrict__ bias,
    const unsigned short* __restrict__ InT, const float* __restrict__ resid,
    void* __restrict__ Out, int M) {
  // A planes = SH[0..2], B planes = SH[3..5]; kT epilogue aliases SH[0..2]
  __shared__ __align__(16) unsigned short SH[6][128 * 32];

  const int b = blockIdx.z;
  const int n0 = blockIdx.x * 128, m0 = blockIdx.y * 128;
  const int tid = threadIdx.x;
  const int lane = tid & 63, wave = tid >> 6;
  const int col = lane & 15, quad = lane >> 4;
  const int wm = (wave >> 1) << 6, wn = (wave & 1) << 6;

  const unsigned short* Ag = Wb + (size_t)m0 * C_;
  const unsigned short* Bg = InT + ((size_t)b * N_ + n0) * C_;

  const int r0 = tid >> 2, c0 = (tid & 3) << 3;

  auto stage = [&](int buf, int k0) {
    GLDS16(Ag + (size_t)r0 * C_ + k0 + c0,        &SH[buf][tid * 8]);
    GLDS16(Ag + (size_t)(r0 + 64) * C_ + k0 + c0, &SH[buf][(tid + 256) * 8]);
    GLDS16(Bg + (size_t)r0 * C_ + k0 + c0,        &SH[3 + buf][tid * 8]);
    GLDS16(Bg + (size_t)(r0 + 64) * C_ + k0 + c0, &SH[3 + buf][(tid + 256) * 8]);
  };

  f32x4 acc[4][4];
#pragma unroll
  for (int i = 0; i < 4; i++)
#pragma unroll
    for (int j = 0; j < 4; j++) acc[i][j] = f32x4{0.f, 0.f, 0.f, 0.f};

  // prologue: tiles 0,1 in flight; wait tile0 only (4 newest may fly)
  stage(0, 0);
  stage(1, 32);
  asm volatile("s_waitcnt vmcnt(4)\n\ts_barrier" ::: "memory");

  for (int it = 0; it < 16; it++) {
    const int cur = it % 3;
    if (it < 14) stage((it + 2) % 3, (it + 2) * 32);  // prefetch distance 2

    bf16x8 af[4], bfr[4];
#pragma unroll
    for (int mt = 0; mt < 4; mt++)
      af[mt] = *(const bf16x8*)&SH[cur][(wm + mt * 16 + col) * 32 + quad * 8];
#pragma unroll
    for (int nt = 0; nt < 4; nt++)
      bfr[nt] = *(const bf16x8*)&SH[3 + cur][(wn + nt * 16 + col) * 32 + quad * 8];
#pragma unroll
    for (int mt = 0; mt < 4; mt++)
#pragma unroll
      for (int nt = 0; nt < 4; nt++)
        acc[mt][nt] = __builtin_amdgcn_mfma_f32_16x16x32_bf16(
            af[mt], bfr[nt], acc[mt][nt], 0, 0, 0);

    if (it < 14) {
      asm volatile("s_waitcnt vmcnt(4)\n\ts_barrier" ::: "memory");
    } else if (it == 14) {
      asm volatile("s_waitcnt vmcnt(0)\n\ts_barrier" ::: "memory");
    }
  }

  const bool kT = OUT_BF16 && (m0 >= 512) && (m0 < 1024);

  if (kT) {
    // Transposed K output via LDS: epi[64 n][136 shorts] per n-half.
    unsigned short* epi = &SH[0][0];
    unsigned short* kt_out =
        (unsigned short*)Out + ((size_t)b * 1536 + 512) * N_ + (m0 - 512);
#pragma unroll
    for (int hf = 0; hf < 2; hf++) {
      __syncthreads();
      if ((wave & 1) == hf) {
#pragma unroll
        for (int mt = 0; mt < 4; mt++) {
          int mloc = wm + mt * 16 + quad * 4;      // 0..127 within block tile
          int mabs = m0 + mloc;
#pragma unroll
          for (int nt = 0; nt < 4; nt++) {
            union { unsigned short s[4]; ushort4 v; } o;
#pragma unroll
            for (int r = 0; r < 4; r++)
              o.s[r] = f2bf(acc[mt][nt][r] + bias[mabs + r]);
            *(ushort4*)&epi[(nt * 16 + col) * 136 + mloc] = o.v;
          }
        }
      }
      __syncthreads();
#pragma unroll
      for (int pass = 0; pass < 4; pass++) {
        int n_l = (tid >> 4) + pass * 16;
        int ch = tid & 15;
        uint4 v = *(const uint4*)&epi[n_l * 136 + ch * 8];
        *(uint4*)(kt_out + (size_t)(n0 + hf * 64 + n_l) * 512 + ch * 8) = v;
      }
    }
    return;
  }

#pragma unroll
  for (int mt = 0; mt < 4; mt++) {
    int mbase = m0 + wm + mt * 16 + quad * 4;
#pragma unroll
    for (int nt = 0; nt < 4; nt++) {
      int n = n0 + wn + nt * 16 + col;
      if constexpr (OUT_BF16) {
#pragma unroll
        for (int r = 0; r < 4; r++) {
          float v = acc[mt][nt][r] + bias[mbase + r];
          ((unsigned short*)Out)[((size_t)b * M + mbase + r) * N_ + n] = f2bf(v);
        }
      } else {
#pragma unroll
        for (int r = 0; r < 4; r++) {
          int m = mbase + r;
          float v = acc[mt][nt][r] + bias[m];
          size_t off = ((size_t)b * M + m) * N_ + n;
          ((float*)Out)[off] = v + resid[off];
        }
      }
    }
  }
}

// ---------- MFMA flash attention, no-max softmax ----------
// Round-13: 512-thread blocks, 8 waves x nt=1 (16 q-rows/wave). Same proven
// sync (dbuf-2, stage-at-top, one __syncthreads/tile; T4-attn reverted -- it
// lost occupancy and changed absmax). Dropping nt=2->1 sheds ~25 VGPR of
// persistent state (qf 16->8, O 32->16): target <=64 VGPR = the 32-waves/CU
// tier -> 4 blocks x 8 waves = 8 waves/SIMD, 2x TLP on a latency-bound
// kernel. If VGPR lands >64 this degrades to today's 4 waves/SIMD (neutral).
// Staging: 1 K + 1 V GLDS16 per thread per tile (512 thr x 16B = 8KB tile).
__device__ __forceinline__ void attn_tile(const bf16x8 (&qf)[2],
                                          const bf16x8 (&kf)[4][2],
                                          const s16x4 (&vf)[4][4],
                                          f32x4 (&O)[4], float& l_i) {
  f32x4 sf[4];
#pragma unroll
  for (int mt = 0; mt < 4; mt++) sf[mt] = f32x4{0.f, 0.f, 0.f, 0.f};
  __builtin_amdgcn_s_setprio(1);
#pragma unroll
  for (int ks = 0; ks < 2; ks++)
#pragma unroll
    for (int mt = 0; mt < 4; mt++)
      sf[mt] = __builtin_amdgcn_mfma_f32_16x16x32_bf16(
          kf[mt][ks], qf[ks], sf[mt], 0, 0, 0);
  __builtin_amdgcn_s_setprio(0);

  // p = exp(s); pack to bf16 by truncation (1 v_perm per pair)
  s16x4 pb[4];
  float lsum = 0.f;
#pragma unroll
  for (int kc = 0; kc < 4; kc++) {
    float e0 = __expf(sf[kc][0]);
    float e1 = __expf(sf[kc][1]);
    float e2 = __expf(sf[kc][2]);
    float e3 = __expf(sf[kc][3]);
    lsum += (e0 + e1) + (e2 + e3);
    unsigned lo = __builtin_amdgcn_perm(__float_as_uint(e1), __float_as_uint(e0), 0x07060302u);
    unsigned hi = __builtin_amdgcn_perm(__float_as_uint(e3), __float_as_uint(e2), 0x07060302u);
    union { unsigned u[2]; s16x4 v; } t;
    t.u[0] = lo; t.u[1] = hi;
    pb[kc] = t.v;
  }
  l_i += lsum;

  __builtin_amdgcn_s_setprio(1);
#pragma unroll
  for (int kc = 0; kc < 4; kc++)
#pragma unroll
    for (int mt = 0; mt < 4; mt++)
      O[mt] = __builtin_amdgcn_mfma_f32_16x16x16bf16_1k(
          vf[mt][kc], pb[kc], O[mt], 0, 0, 0);
  __builtin_amdgcn_s_setprio(0);
}

template <int NB, int BOFF>
__global__ __launch_bounds__(512, 2) void attn_mfma(
    const unsigned short* __restrict__ qkv, unsigned short* __restrict__ aoT) {
  __shared__ __align__(16) unsigned short KtL[2][64 * 64];
  __shared__ __align__(16) unsigned short VsL[2][64 * 64];

  const int tid = threadIdx.x;
  const int wave = tid >> 6, lane = tid & 63;
  const int quad = lane >> 4, col = lane & 15;
  const int bi = blockIdx.x;
  const int hh = bi & 7;                    // bi%8==head -> XCD-grouped
  const int bq = bi >> 3;                   // 0 .. 8*NB-1
  const int qb = bq / NB;                   // 0..7 (compile-time div)
  const int b  = BOFF + (bq - qb * NB);
  const int qg = qb * 128 + wave * 16 + col;   // this wave's q row (nt=1)

  const unsigned short* qp  = qkv + ((size_t)b * 1536 + hh * 64) * N_;           // [d][N]
  const unsigned short* ktp = qkv + ((size_t)b * 1536 + 512) * N_ + hh * 64;     // [key][512]
  const unsigned short* vp  = qkv + ((size_t)b * 1536 + 1024 + hh * 64) * N_;    // [d][N]

  // staging decomposition: row 0..63 + swizzled 16B chunk (1 K + 1 V per thread)
  const int sr = tid >> 3;                          // 0..63
  const int sw8 = (((tid & 7) ^ (sr & 7)) << 3);    // swizzled chunk, in shorts

  // Q B-fragments pre-scaled by 0.125 (exact: exponent shift under RNE).
  bf16x8 qf[2];
#pragma unroll
  for (int ks = 0; ks < 2; ks++) {
    union { unsigned short s[8]; bf16x8 v; } t;
#pragma unroll
    for (int j = 0; j < 8; j++) {
      int d = ks * 32 + quad * 8 + j;
      t.s[j] = f2bf(0.125f * bf2f(qp[(size_t)d * N_ + qg]));
    }
    qf[ks] = t.v;
  }

  float l_i = 0.f;
  f32x4 O[4];
#pragma unroll
  for (int mt = 0; mt < 4; mt++) O[mt] = f32x4{0.f, 0.f, 0.f, 0.f};

  // stage tile 0
  GLDS16(ktp + (size_t)sr * 512 + sw8, &KtL[0][tid * 8]);
  GLDS16(vp + (size_t)sr * N_ + sw8,   &VsL[0][tid * 8]);
  __syncthreads();

  for (int kt = 0; kt < 16; kt++) {
    const int cur = kt & 1;
    if (kt < 15) {
      GLDS16(ktp + (size_t)((kt + 1) * 64 + sr) * 512 + sw8, &KtL[cur ^ 1][tid * 8]);
      GLDS16(vp + (size_t)sr * N_ + (kt + 1) * 64 + sw8,     &VsL[cur ^ 1][tid * 8]);
    }

    // K A-fragments (16x16x32): b128, swizzle-matched
    bf16x8 kf[4][2];
#pragma unroll
    for (int mt = 0; mt < 4; mt++) {
      int key = 16 * mt + col;
#pragma unroll
      for (int ks = 0; ks < 2; ks++)
        kf[mt][ks] = *(const bf16x8*)
            &KtL[cur][key * 64 + (((ks * 4 + quad) ^ (col & 7)) << 3)];
    }
    // V A-fragments (16x16x16): b64, swizzle-matched at 8B granularity
    s16x4 vf[4][4];
#pragma unroll
    for (int mt = 0; mt < 4; mt++) {
      int d = 16 * mt + col;
#pragma unroll
      for (int kc = 0; kc < 4; kc++)
        vf[mt][kc] = *(const s16x4*)
            &VsL[cur][d * 64 + (((kc * 4 + quad) ^ ((col & 7) << 1)) << 2)];
    }

    attn_tile(qf, kf, vf, O, l_i);

    if (kt < 15) __syncthreads();
  }

  float ls = l_i;
  ls += __shfl_xor(ls, 16, 64);
  ls += __shfl_xor(ls, 32, 64);
  float inv = 1.f / ls;
  unsigned short* dst = aoT + ((size_t)b * N_ + qg) * C_ + hh * 64;
#pragma unroll
  for (int mt = 0; mt < 4; mt++) {
    union { unsigned short s[4]; ushort4 v; } o;
#pragma unroll
    for (int r = 0; r < 4; r++) o.s[r] = f2bf(O[mt][r] * inv);
    *(ushort4*)(dst + mt * 16 + quad * 4) = o.v;
  }
}

extern "C" void kernel_launch(void* const* d_in, const int* in_sizes, int n_in,
                              void* d_out, int out_size, void* d_ws, size_t ws_size,
                              hipStream_t stream) {
  (void)in_sizes; (void)n_in; (void)out_size; (void)ws_size;
  const float* x      = (const float*)d_in[0];
  const float* gamma  = (const float*)d_in[1];
  const float* beta   = (const float*)d_in[2];
  const float* w_qkv  = (const float*)d_in[3];
  const float* b_qkv  = (const float*)d_in[4];
  const float* w_proj = (const float*)d_in[5];
  const float* b_proj = (const float*)d_in[6];
  float* out = (float*)d_out;

  unsigned short* hT   = (unsigned short*)d_ws;                 // B*N*C bf16
  unsigned short* qkvb = hT + (size_t)B_ * N_ * C_;             // B*3C*N bf16 (K region = KT[b][n][512])
  unsigned short* aoT  = hT;                                    // reuse
  unsigned short* wqb  = qkvb + (size_t)B_ * 1536 * N_;         // 3C*C bf16
  unsigned short* wpb  = wqb + (size_t)1536 * 512;              // C*C bf16
  float* stats = (float*)(wpb + (size_t)512 * 512);             // 512 x {mean,rstd}

  prep_kernel<<<dim3(1024 + 512), dim3(256), 0, stream>>>(w_qkv, w_proj, wqb, wpb, x, stats);
  gn_norm<<<dim3(512), dim3(256), 0, stream>>>(x, gamma, beta, stats, hT);
  gemm_mfma<1><<<dim3(8, 12, 16), dim3(256), 0, stream>>>(
      wqb, b_qkv, hT, (const float*)nullptr, (void*)qkvb, 1536);
  attn_mfma<16, 0><<<dim3(1024), dim3(512), 0, stream>>>(qkvb, aoT);
  gemm_mfma<0><<<dim3(8, 4, 16), dim3(256), 0, stream>>>(
      wpb, b_proj, aoT, x, (void*)out, 512);
}